// Round 1
// baseline (57902.026 us; speedup 1.0000x reference)
//
#include <hip/hip_runtime.h>

#define HH 128      // hidden size
#define G4 512      // 4*HH gates
#define TT 102400   // sequence length
#define BB 8        // batch

typedef _Float16 v2h __attribute__((ext_vector_type(2)));

#if __has_builtin(__builtin_amdgcn_fdot2)
#define FDOT2(a, b, c) __builtin_amdgcn_fdot2((a), (b), (c), false)
#else
static __device__ __forceinline__ float fdot2_fb(v2h a, v2h b, float c) {
    return fmaf((float)a[0], (float)b[0], fmaf((float)a[1], (float)b[1], c));
}
#define FDOT2(a, b, c) fdot2_fb((a), (b), (c))
#endif

// DPP lane move (VALU pipe): 0xB1=xor1(quad), 0x4E=xor2(quad), 0x141=xor7(row-half mirror)
template<int CTRL>
__device__ __forceinline__ float dpp_mov(float v) {
    return __int_as_float(
        __builtin_amdgcn_update_dpp(0, __float_as_int(v), CTRL, 0xF, 0xF, true));
}

__device__ __forceinline__ float tanh_f(float x) {
    return fmaf(2.0f, __builtin_amdgcn_rcpf(1.0f + __expf(-2.0f * x)), -1.0f);
}

// R12: light barrier — LDS-visibility only. __syncthreads() drains
// vmcnt(0) too, which put the per-step ring STORE ack (~200-500cy) and the
// t4+1 global prefetch latency on the serial chain critical path. The only
// cross-wave hazard per step is the hh LDS double-buffer hand-off, which
// needs lgkmcnt(0)+s_barrier only. sched_barrier(0) fences per rule #18
// (hipcc hoists non-memory ops past inline-asm waitcnt); "memory" clobber
// pins the ds_writes above the wait. Global ring/xp stores are consumed
// only by the NEXT kernel launch (stream order + kernel-end flush).
static __device__ __forceinline__ void bar_lds() {
    __builtin_amdgcn_sched_barrier(0);
    asm volatile("s_waitcnt lgkmcnt(0)" ::: "memory");
    __builtin_amdgcn_s_barrier();
    __builtin_amdgcn_sched_barrier(0);
}

union HI { int i; v2h h; };

// ---------------------------------------------------------------------------
// R7-verified reduce-to-distinct: lane j of each 8-lane group covers
// k in [16j,16j+16) of 8 gate rows (rho: bit0=cell, bits2:1=gate).
// Keep-functionals (GF(2)): phi1=j0^j2 (mask1), phi2=j0^j1 (mask2), phi3=j2
// (mask7). Lane j ends with the FULL 128-dot of row
// (cell=j0^j2, gate=2*(j0^j1)+j2). cell0 {i@0,f@7,g@2,o@5}, cell1 {i@3,f@4,g@1,o@6}.
// ---------------------------------------------------------------------------
__device__ __forceinline__ float dotred(const v2h w[8][8],
                                        const _Float16* __restrict__ hsl,
                                        bool bp1, bool bp2, bool bp3) {
    const int4* hp4 = (const int4*)hsl;     // 2x ds_read_b128 (16 halfs)
    int4 ha = hp4[0], hb = hp4[1];
    int hp[8] = {ha.x, ha.y, ha.z, ha.w, hb.x, hb.y, hb.z, hb.w};
    float acc[8];
#pragma unroll
    for (int r = 0; r < 8; ++r) acc[r] = 0.f;
#pragma unroll
    for (int i = 0; i < 8; ++i) {
        HI u; u.i = hp[i];
#pragma unroll
        for (int r = 0; r < 8; ++r) acc[r] = FDOT2(w[r][i], u.h, acc[r]);
    }
    // round 1 (mask 1): reduce cell bit; keep rho0 == bp1
    float b0[4];
#pragma unroll
    for (int m = 0; m < 4; ++m) {
        float send = bp1 ? acc[2 * m] : acc[2 * m + 1];
        float keep = bp1 ? acc[2 * m + 1] : acc[2 * m];
        b0[m] = keep + dpp_mov<0xB1>(send);
    }
    // round 2 (mask 2): reduce gate-hi bit; keep g1 == bp2 (= j0^j1)
    float d0[2];
#pragma unroll
    for (int i = 0; i < 2; ++i) {
        float send = bp2 ? b0[i] : b0[i + 2];
        float keep = bp2 ? b0[i + 2] : b0[i];
        d0[i] = keep + dpp_mov<0x4E>(send);
    }
    // round 3 (mask 7): reduce gate-lo bit; keep g0 == bp3 (= j2)
    float send = bp3 ? d0[0] : d0[1];
    float keep = bp3 ? d0[1] : d0[0];
    return keep + dpp_mov<0x141>(send);
}

// load this lane's fp16 weight slices: rows rho=0..7 -> W row 2Q+(rho&1)+128*(rho>>1)
__device__ __forceinline__ void load_w8h(const float* __restrict__ W,
                                         int Q, int j, v2h w[8][8]) {
#pragma unroll
    for (int r = 0; r < 8; ++r) {
        int row = 2 * Q + (r & 1) + 128 * (r >> 1);
        const float4* rp = (const float4*)(W + (size_t)row * HH + 16 * j);
#pragma unroll
        for (int i = 0; i < 4; ++i) {
            float4 f = rp[i];
            w[r][2 * i]     = (v2h){(_Float16)f.x, (_Float16)f.y};
            w[r][2 * i + 1] = (v2h){(_Float16)f.z, (_Float16)f.w};
        }
    }
}

// ---------------------------------------------------------------------------
// One pipeline slot (512 threads/block) — R7/R11-verified structure:
//   blocks 0..7  = stage A (layer0 chain, chunk c)
//   blocks 8..15 = stage C (layer1 chain, chunk c-2)
//   blocks 16..79= stage B (xp1 GEMM, chunk c-1): 8 batch x 8 t-slice
// Stages independent within a launch; stream order gives producer->consumer
// ordering across launches. Chain CUs are VALU-issue-bound (R10 diagnostic);
// R12 removes the per-step vmcnt(0) drain from the chain critical path.
// ---------------------------------------------------------------------------
__global__ void __launch_bounds__(512, 2)
lstm_slot_kernel(
    const float* __restrict__ x,
    const float* __restrict__ Wih0, const float* __restrict__ Whh0,
    const float* __restrict__ bih0, const float* __restrict__ bhh0,
    const float* __restrict__ Wih1, const float* __restrict__ Whh1,
    const float* __restrict__ bih1, const float* __restrict__ bhh1,
    float* __restrict__ h1s, float* __restrict__ c1s,
    float* __restrict__ h2s, float* __restrict__ c2s,
    double* __restrict__ pooled,
    _Float16* __restrict__ h1ring,  // [2][B][chunkT][HH]   fp16
    float* __restrict__ xpring,     // [2][B][chunkT][HH][4] (t,cell,gate) fp32
    int c, int chunkT, int nchunks)
{
    __shared__ __align__(32) _Float16 hh[2 * HH];
    const int t = threadIdx.x;
    const int Q = t >> 3;                 // 8-lane group -> cells {2Q, 2Q+1}
    const int j = t & 7;
    const bool bp1 = ((j ^ (j >> 2)) & 1) != 0;   // phi1 = j0^j2 (cell bit)
    const bool bp2 = ((j ^ (j >> 1)) & 1) != 0;   // phi2 = j0^j1 (gate hi)
    const bool bp3 = ((j >> 2) & 1) != 0;         // phi3 = j2    (gate lo)
    const int cellj = bp1 ? 1 : 0;
    const int gatej = (bp2 ? 2 : 0) + (bp3 ? 1 : 0);
    const int myc   = 2 * Q + cellj;
    const int myrow = myc + 128 * gatej;
    const bool owner = (gatej == 0);              // gate-i lanes: j in {0,3}
    // branchless activation constants: sigmoid for i,f,o; tanh for g(=gate2)
    const bool isg = (gatej == 2);
    const float fe = isg ? -2.f : -1.f;
    const float fm = isg ?  2.f :  1.f;
    const float fa = isg ? -1.f :  0.f;

    if (blockIdx.x < 16) {
        // =============== chain stages (A: layer0, C: layer1) ===============
        const bool isA = (blockIdx.x < 8);
        const int cc = isA ? c : (c - 2);
        if (cc < 0 || cc >= nchunks) return;
        const int b = blockIdx.x & 7;

        v2h w[8][8];
        load_w8h(isA ? Whh0 : Whh1, Q, j, w);
        float bias_l = 0.f, wih_l = 0.f;
        if (isA) { bias_l = bih0[myrow] + bhh0[myrow]; wih_l = Wih0[myrow]; }

        float* hst = isA ? h1s : h2s;
        float* cst = isA ? c1s : c2s;
        float c_reg = cst[b * HH + myc];
        if (t < HH) hh[t] = (_Float16)hst[b * HH + t];

        _Float16* ringp = h1ring + ((size_t)((c & 1) * BB + b)) * (size_t)chunkT * HH;
        const float4* xb4 = (const float4*)(x + (size_t)b * TT + (size_t)cc * chunkT);
        const float* xps = xpring
            + ((size_t)((cc & 1) * BB + b)) * (size_t)chunkT * G4 + 4 * myc + gatej;

        const int nt4 = chunkT >> 2;
        float4 xq = {0, 0, 0, 0};
        float xpc[4] = {0, 0, 0, 0};
        if (isA) xq = xb4[0];
        else {
#pragma unroll
            for (int u = 0; u < 4; ++u) xpc[u] = xps[(size_t)u * G4];
        }
        double pacc = 0.0;
        float hfin = 0.f;
        bar_lds();

        for (int t4 = 0; t4 < nt4; ++t4) {
            float4 xqn = {0, 0, 0, 0};
            float xpn[4] = {0, 0, 0, 0};
            if (isA) {
                if (t4 + 1 < nt4) xqn = xb4[t4 + 1];
            } else if (t4 + 1 < nt4) {
#pragma unroll
                for (int u = 0; u < 4; ++u)
                    xpn[u] = xps[(size_t)(t4 * 4 + 4 + u) * G4];
            }
#pragma unroll
            for (int u = 0; u < 4; ++u) {
                const int buf = u & 1;                 // static step parity
                float sfin = dotred(w, hh + buf * HH + 16 * j, bp1, bp2, bp3);
                float pre;
                if (isA) {
                    float xt = (u == 0) ? xq.x : (u == 1) ? xq.y
                             : (u == 2) ? xq.z : xq.w;
                    pre = fmaf(xt, wih_l, sfin + bias_l);
                } else {
                    pre = sfin + xpc[u];
                }
                // one activation per lane (its own gate)
                float e  = __expf(pre * fe);
                float rr = __builtin_amdgcn_rcpf(1.0f + e);
                float act = fmaf(fm, rr, fa);
                // gate-gather at owners (gate i): f@j^7, g@j^2, o@j^5
                float t1 = dpp_mov<0x141>(act);   // act[j^7] = f
                float t2 = dpp_mov<0x4E>(act);    // act[j^2] = g
                float t3 = dpp_mov<0x4E>(t1);     // act[j^5] = o
                c_reg = fmaf(t1, c_reg, act * t2);   // c = f*c + i*g
                float th = tanh_f(c_reg);
                float hv = t3 * th;                  // h = o*tanh(c)
                hfin = hv;
                if (owner) {
                    hh[(buf ^ 1) * HH + myc] = (_Float16)hv;
                    if (isA) ringp[(size_t)(t4 * 4 + u) * HH + myc] = (_Float16)hv;
                    else     pacc += (double)hv;
                }
                bar_lds();
            }
            xq = xqn;
            if (!isA) {
#pragma unroll
                for (int u = 0; u < 4; ++u) xpc[u] = xpn[u];
            }
        }
        if (owner) {
            cst[b * HH + myc] = c_reg;
            hst[b * HH + myc] = hfin;
            if (!isA) pooled[b * HH + myc] += pacc;
        }

    } else {
        // ---------------- stage B: xp1 = Wih1 @ h1 + bias, chunk c-1 -------
        const int bc = c - 1;
        if (bc < 0 || bc >= nchunks) return;
        const int ib = blockIdx.x - 16;       // 0..63
        const int bb = ib >> 3;               // batch
        const int sl = ib & 7;                // t-slice (stride 8)
        v2h w[8][8];
        load_w8h(Wih1, Q, j, w);
        const float bias_l = bih1[myrow] + bhh1[myrow];
        const _Float16* hrp = h1ring
            + ((size_t)((bc & 1) * BB + bb)) * (size_t)chunkT * HH;
        float* xpw = xpring + ((size_t)((bc & 1) * BB + bb)) * (size_t)chunkT * G4;
        if (t < HH) hh[t] = hrp[(size_t)sl * HH + t];
        bar_lds();
        int pb = 0;
        for (int tt = sl; tt < chunkT; tt += 8) {
            int ttn = tt + 8;
            bool pf = (t < HH) && (ttn < chunkT);
            _Float16 hn = (_Float16)0.f;
            if (pf) hn = hrp[(size_t)ttn * HH + t];          // prefetch
            float sfin = dotred(w, hh + pb * HH + 16 * j, bp1, bp2, bp3);
            if (pf) hh[(pb ^ 1) * HH + t] = hn;
            xpw[(size_t)tt * G4 + 4 * myc + gatej] = sfin + bias_l;
            bar_lds();
            pb ^= 1;
        }
    }
}

// ---------------- head: mean-pool (done) -> FC+ReLU -> FC ------------------
__global__ void head_kernel(const double* __restrict__ pooled,
                            const float* __restrict__ fcW1, const float* __restrict__ fcb1,
                            const float* __restrict__ fcW2, const float* __restrict__ fcb2,
                            float* __restrict__ out)
{
    __shared__ float p_s[HH];
    __shared__ float hid_s[64];
    const int b = blockIdx.x, t = threadIdx.x;
    if (t < HH) p_s[t] = (float)(pooled[b * HH + t] * (1.0 / (double)TT));
    __syncthreads();
    if (t < 64) {
        float acc = fcb1[t];
#pragma unroll 8
        for (int k = 0; k < HH; ++k) acc = fmaf(p_s[k], fcW1[t * HH + k], acc);
        hid_s[t] = fmaxf(acc, 0.f);
    }
    __syncthreads();
    if (t < 11) {
        float acc = fcb2[t];
#pragma unroll
        for (int k = 0; k < 64; ++k) acc = fmaf(hid_s[k], fcW2[t * 64 + k], acc);
        out[b * 11 + t] = acc;
    }
}

// ---------------------------------------------------------------------------
extern "C" void kernel_launch(void* const* d_in, const int* in_sizes, int n_in,
                              void* d_out, int out_size, void* d_ws, size_t ws_size,
                              hipStream_t stream)
{
    const float* x    = (const float*)d_in[0];
    const float* Wih0 = (const float*)d_in[1];
    const float* Whh0 = (const float*)d_in[2];
    const float* bih0 = (const float*)d_in[3];
    const float* bhh0 = (const float*)d_in[4];
    const float* Wih1 = (const float*)d_in[5];
    const float* Whh1 = (const float*)d_in[6];
    const float* bih1 = (const float*)d_in[7];
    const float* bhh1 = (const float*)d_in[8];
    const float* fcW1 = (const float*)d_in[9];
    const float* fcb1 = (const float*)d_in[10];
    const float* fcW2 = (const float*)d_in[11];
    const float* fcb2 = (const float*)d_in[12];
    float* out = (float*)d_out;

    // ---- workspace layout ----
    char* wsp = (char*)d_ws;
    float*  h1s    = (float*) (wsp + 0);
    float*  c1s    = (float*) (wsp + 4096);
    float*  h2s    = (float*) (wsp + 8192);
    float*  c2s    = (float*) (wsp + 12288);
    double* pooled = (double*)(wsp + 16384);          // 8 KB
    const size_t STATE_BYTES = 24576;

    // chunkT=800 (vs 1600): fill factor 130/128=1.016 (was 1.031); rings
    // shrink to ~14.7MB (L2-resident, 32MB aggregate). R11 showed chunk
    // shrink beats its fill arithmetic via cache residency — one more notch.
    // per-t ring bytes: h1 fp16 4096 + xp fp32 32768 = 36864
    static const int cands[] = {800, 400, 160, 80, 40, 8};
    int chunkT = 8;
    for (int i = 0; i < 6; ++i) {
        size_t need = STATE_BYTES + (size_t)36864 * (size_t)cands[i];
        if (need <= ws_size) { chunkT = cands[i]; break; }
    }
    const int nchunks = TT / chunkT;

    _Float16* h1ring = (_Float16*)(wsp + STATE_BYTES);
    float* xpring = (float*)(wsp + STATE_BYTES + (size_t)2 * BB * chunkT * HH * 2);

    // zero persistent state (h/c/pooled); ws is re-poisoned before every call
    hipMemsetAsync(d_ws, 0, STATE_BYTES, stream);

    // pipeline: slot c runs A(c) || B(c-1) || C(c-2)
    const int nslots = nchunks + 2;
    for (int c = 0; c < nslots; ++c) {
        lstm_slot_kernel<<<80, 512, 0, stream>>>(
            x, Wih0, Whh0, bih0, bhh0, Wih1, Whh1, bih1, bhh1,
            h1s, c1s, h2s, c2s, pooled, h1ring, xpring,
            c, chunkT, nchunks);
    }
    head_kernel<<<BB, 128, 0, stream>>>(pooled, fcW1, fcb1, fcW2, fcb2, out);
}